// Round 5
// baseline (363.463 us; speedup 1.0000x reference)
//
#include <hip/hip_runtime.h>
#include <cstdint>

// ---------------------------------------------------------------------------
// minerva_transform: logits = (l2(Xe) @ l2(De)^T)^3 @ rh ; preds = sigmoid
// R5: TWO dispatches (R4's grid-barrier persistent kernel failed on a
// stale-clean-L2 race + serialization; reverting to dispatch-boundary
// ordering which is HSA-guaranteed).
//   1) k_embed: reads fp32 X/D/g_w directly (cvt in staging, ds_write path),
//      XCD-pinned grid, writes Eb bf16 + race-free norm2 partials + zeroes lg.
//   2) k_minerva: R3's proven MFMA GEMM, XCD-pinned grid (each XCD's D-panel
//      fits its 4MB L2), rh inline, norm folded in epilogue, last-done-block
//      finalize reading lg with AGENT-scope atomic loads (cache-bypass, no
//      fence subtleties).  Done-counter self-resets -> graph-replay-safe.
// ---------------------------------------------------------------------------

typedef __attribute__((ext_vector_type(4))) float  f32x4;
typedef __attribute__((ext_vector_type(8))) __bf16 bf16x8;

constexpr int B = 4096, N = 20000, F = 768, E = 512;
constexpr int NROWS = 24576;          // padded g-rows (192 row-tiles)
constexpr unsigned MINERVA_BLOCKS = 32u * 160u;   // 5120 (nt padded to 160)

#define AS1CAST(p) ((__attribute__((address_space(1))) unsigned int*)(uintptr_t)(p))
#define AS3CAST(p) ((__attribute__((address_space(3))) unsigned int*)(uintptr_t)(p))

__device__ __forceinline__ void gload_lds16(const void* g, void* l) {
  __builtin_amdgcn_global_load_lds(AS1CAST(g), AS3CAST(l), 16, 0, 0);
}

__device__ unsigned g_done = 0;   // self-resetting; not in ws (survives poison)

// ------------------------- embedding GEMM (fp32 in) ------------------------
// grid = bx(4) * by(192 padded): bid = bx*192 + by  ->  XCD = bid&7 = by&7.
// Row-tiles: by 0..31 = X, 32..188 = D, 189..191 idle-padded.
// Stages fp32 -> bf16 into XOR-swizzled LDS via ds_write_b128 (no prep pass).
// Outputs: Eb[g0+row][col] bf16, norm2p[bx*NROWS + g0+row] partial sumsq.

__global__ __launch_bounds__(256, 3)
void k_embed(const float* __restrict__ X, const float* __restrict__ D,
             const float* __restrict__ G, const float* __restrict__ bias,
             __bf16* __restrict__ Eb, float* __restrict__ norm2p,
             float* __restrict__ lg) {
  __shared__ __bf16 As[128 * 64];
  __shared__ __bf16 Bs[128 * 64];
  __shared__ float lsum[128];
  const int tid  = threadIdx.x;
  const int bid  = blockIdx.x;
  const int wave = tid >> 6;
  const int lane = tid & 63;

  if (bid == 0) {               // zero logits for minerva's atomics (next
    for (int i = tid; i < B; i += 256) lg[i] = 0.0f;   // dispatch: HSA-ordered)
  }

  const int bx = bid / 192;     // e-tile 0..3
  const int by = bid % 192;     // row-tile (XCD-pinned: by&7)
  const bool isX = (by < 32);
  const float* A = isX ? X : D;
  const int m0 = isX ? by * 128 : (by - 32) * 128;
  const int Mr = isX ? B : N;
  const int g0 = by * 128;
  const int n0 = bx * 128;
  if (tid < 128) lsum[tid] = 0.0f;

  // staging geometry: thread t -> rows rbase+32q, colgrp cg (8 elems = 16B),
  // stored at swizzled slot cg^(row&7)  (row&7 == rbase&7)
  const int cg    = tid & 7;
  const int rbase = tid >> 3;
  const int sw    = ((cg ^ (rbase & 7)) * 8);
  size_t aoff[4], boff[4];
  int    lidx[4];
#pragma unroll
  for (int q = 0; q < 4; ++q) {
    const int rt = rbase + 32 * q;
    int arow = m0 + rt; if (arow >= Mr) arow = Mr - 1;
    aoff[q] = (size_t)arow * F + cg * 8;
    boff[q] = (size_t)(n0 + rt) * F + cg * 8;
    lidx[q] = rt * 64 + sw;
  }

  const int mw = (wave & 1) * 64;
  const int nw = (wave >> 1) * 64;
  const int quad = lane >> 4;
  const int l15  = lane & 15;
  f32x4 acc[4][4] = {};

  for (int kb = 0; kb < F; kb += 64) {
#pragma unroll
    for (int q = 0; q < 4; ++q) {
      const float4 v0 = *(const float4*)(A + aoff[q] + kb);
      const float4 v1 = *(const float4*)(A + aoff[q] + kb + 4);
      bf16x8 t;
      t[0] = (__bf16)v0.x; t[1] = (__bf16)v0.y; t[2] = (__bf16)v0.z; t[3] = (__bf16)v0.w;
      t[4] = (__bf16)v1.x; t[5] = (__bf16)v1.y; t[6] = (__bf16)v1.z; t[7] = (__bf16)v1.w;
      *(bf16x8*)&As[lidx[q]] = t;
    }
#pragma unroll
    for (int q = 0; q < 4; ++q) {
      const float4 v0 = *(const float4*)(G + boff[q] + kb);
      const float4 v1 = *(const float4*)(G + boff[q] + kb + 4);
      bf16x8 t;
      t[0] = (__bf16)v0.x; t[1] = (__bf16)v0.y; t[2] = (__bf16)v0.z; t[3] = (__bf16)v0.w;
      t[4] = (__bf16)v1.x; t[5] = (__bf16)v1.y; t[6] = (__bf16)v1.z; t[7] = (__bf16)v1.w;
      *(bf16x8*)&Bs[lidx[q]] = t;
    }
    __syncthreads();
#pragma unroll
    for (int h = 0; h < 2; ++h) {
      bf16x8 af[4], bfr[4];
#pragma unroll
      for (int i = 0; i < 4; ++i) {
        const int rr = mw + i * 16 + l15;
        af[i] = *(const bf16x8*)&As[rr * 64 + ((quad + h * 4) ^ (rr & 7)) * 8];
      }
#pragma unroll
      for (int j = 0; j < 4; ++j) {
        const int rr = nw + j * 16 + l15;
        bfr[j] = *(const bf16x8*)&Bs[rr * 64 + ((quad + h * 4) ^ (rr & 7)) * 8];
      }
#pragma unroll
      for (int i = 0; i < 4; ++i)
#pragma unroll
        for (int j = 0; j < 4; ++j)
          acc[i][j] = __builtin_amdgcn_mfma_f32_16x16x32_bf16(af[i], bfr[j], acc[i][j], 0, 0, 0);
    }
    __syncthreads();
  }

  // epilogue: bf16 store + row sum-of-squares (C/D: col=l15, row=quad*4+rr)
#pragma unroll
  for (int i = 0; i < 4; ++i) {
    float part[4] = {0.0f, 0.0f, 0.0f, 0.0f};
#pragma unroll
    for (int j = 0; j < 4; ++j) {
      const int col = n0 + nw + j * 16 + l15;
      const float bv = bias[col];
#pragma unroll
      for (int rr = 0; rr < 4; ++rr) {
        const int row = mw + i * 16 + quad * 4 + rr;
        if (m0 + row < Mr) {
          const __bf16 hv = (__bf16)(acc[i][j][rr] + bv);
          Eb[(size_t)(g0 + row) * E + col] = hv;
          const float vb = (float)hv;
          part[rr] += vb * vb;
        }
      }
    }
#pragma unroll
    for (int rr = 0; rr < 4; ++rr) {
      float v = part[rr];
      v += __shfl_xor(v, 1);
      v += __shfl_xor(v, 2);
      v += __shfl_xor(v, 4);
      v += __shfl_xor(v, 8);
      if (l15 == 0) atomicAdd(&lsum[mw + i * 16 + quad * 4 + rr], v);
    }
  }
  __syncthreads();
  if (tid < 128) norm2p[(size_t)bx * NROWS + g0 + tid] = lsum[tid];  // race-free slot
}

// ------------------------- fused Minerva GEMM + finalize -------------------
// grid = mt(32) * nt(160 padded): bid = mt*160 + nt -> XCD = nt&7.
// Each XCD's 20 D-tiles (2.5MB) live in its 4MB L2 for the whole kernel.

__global__ __launch_bounds__(256, 3)
void k_minerva(const __bf16* __restrict__ Eb, const float* __restrict__ norm2p,
               const float* __restrict__ r, const float* __restrict__ hw,
               const float* __restrict__ hb, float* __restrict__ lg,
               float* __restrict__ out) {
  __shared__ __bf16 As[128 * 64];
  __shared__ __bf16 Bs[128 * 64];
  __shared__ float lsum[128];
  __shared__ int amLast;
  const int tid  = threadIdx.x;
  const int bid  = blockIdx.x;
  const int wave = tid >> 6;
  const int lane = tid & 63;
  const int mt = bid / 160;
  const int nt = bid % 160;            // XCD-pinned: nt&7

  if (nt < 157) {
    const int m0 = mt * 128, n0 = nt * 128;
    if (tid < 128) lsum[tid] = 0.0f;
    const __bf16* Xe = Eb;
    const __bf16* De = Eb + (size_t)B * E;

    const int srow = tid >> 3;
    const int scg  = (tid & 7) ^ (srow & 7);
    const __bf16* ga[4]; const __bf16* gb[4]; int li[4];
#pragma unroll
    for (int q = 0; q < 4; ++q) {
      const int row = srow + 32 * q;
      const int arow = m0 + row;                     // < 4096 always
      int brow = n0 + row; if (brow >= N) brow = N - 1;
      ga[q] = Xe + (size_t)arow * E + scg * 8;
      gb[q] = De + (size_t)brow * E + scg * 8;
      li[q] = q * 2048 + tid * 8;
    }

    const int mw = (wave & 1) * 64;
    const int nw = (wave >> 1) * 64;
    const int quad = lane >> 4;
    const int l15  = lane & 15;
    f32x4 acc[4][4] = {};

    for (int kb = 0; kb < E; kb += 64) {
#pragma unroll
      for (int q = 0; q < 4; ++q) gload_lds16(ga[q] + kb, &As[li[q]]);
#pragma unroll
      for (int q = 0; q < 4; ++q) gload_lds16(gb[q] + kb, &Bs[li[q]]);
      __syncthreads();
#pragma unroll
      for (int h = 0; h < 2; ++h) {
        bf16x8 af[4], bfr[4];
#pragma unroll
        for (int i = 0; i < 4; ++i) {
          const int rr = mw + i * 16 + l15;
          af[i] = *(const bf16x8*)&As[rr * 64 + ((quad + h * 4) ^ (rr & 7)) * 8];
        }
#pragma unroll
        for (int j = 0; j < 4; ++j) {
          const int rr = nw + j * 16 + l15;
          bfr[j] = *(const bf16x8*)&Bs[rr * 64 + ((quad + h * 4) ^ (rr & 7)) * 8];
        }
#pragma unroll
        for (int i = 0; i < 4; ++i)
#pragma unroll
          for (int j = 0; j < 4; ++j)
            acc[i][j] = __builtin_amdgcn_mfma_f32_16x16x32_bf16(af[i], bfr[j], acc[i][j], 0, 0, 0);
      }
      __syncthreads();
    }

    // epilogue: s^3*rh = acc^3 * ix^3 * (id^3*rh);  rh computed inline
    const float hwv = hw[0], hbv = hb[0];
    float id3rh[4];
#pragma unroll
    for (int j = 0; j < 4; ++j) {
      const int col = n0 + nw + j * 16 + l15;
      if (col < N) {
        const int gr = B + col;
        const float nd2 = norm2p[gr] + norm2p[NROWS + gr]
                        + norm2p[2 * NROWS + gr] + norm2p[3 * NROWS + gr];
        const float id = 1.0f / fmaxf(sqrtf(nd2), 1e-12f);
        const float rhv = (2.0f * r[col] - 1.0f) * hwv + hbv;
        id3rh[j] = id * id * id * rhv;
      } else id3rh[j] = 0.0f;   // kills padded/clamped cols
    }
#pragma unroll
    for (int i = 0; i < 4; ++i) {
      float ix3[4];
#pragma unroll
      for (int rr = 0; rr < 4; ++rr) {
        const int row = m0 + mw + i * 16 + quad * 4 + rr;   // < 4096
        const float nx2 = norm2p[row] + norm2p[NROWS + row]
                        + norm2p[2 * NROWS + row] + norm2p[3 * NROWS + row];
        const float ix = 1.0f / fmaxf(sqrtf(nx2), 1e-12f);
        ix3[rr] = ix * ix * ix;
      }
      float part[4] = {0.0f, 0.0f, 0.0f, 0.0f};
#pragma unroll
      for (int j = 0; j < 4; ++j)
#pragma unroll
        for (int rr = 0; rr < 4; ++rr) {
          const float a = acc[i][j][rr];
          part[rr] = fmaf(a * a * a, id3rh[j], part[rr]);
        }
#pragma unroll
      for (int rr = 0; rr < 4; ++rr) {
        float v = part[rr] * ix3[rr];
        v += __shfl_xor(v, 1);
        v += __shfl_xor(v, 2);
        v += __shfl_xor(v, 4);
        v += __shfl_xor(v, 8);
        if (l15 == 0) atomicAdd(&lsum[mw + i * 16 + quad * 4 + rr], v);
      }
    }
    __syncthreads();
    if (tid < 128) atomicAdd(&lg[m0 + tid], lsum[tid]);   // device-scope
  }

  // ---- last-done-block finalize (no grid barrier, no co-residency req) ----
  __syncthreads();   // drains this block's vmcnt -> its lg atomics complete
  if (tid == 0) {
    __builtin_amdgcn_fence(__ATOMIC_RELEASE, "agent");
    const unsigned prev =
        __hip_atomic_fetch_add(&g_done, 1u, __ATOMIC_ACQ_REL, __HIP_MEMORY_SCOPE_AGENT);
    amLast = (prev == MINERVA_BLOCKS - 1u);
    if (amLast)
      __hip_atomic_store(&g_done, 0u, __ATOMIC_RELAXED, __HIP_MEMORY_SCOPE_AGENT);  // replay-safe
  }
  __syncthreads();
  if (amLast) {
    for (int i = tid; i < B; i += 256) {
      // agent-scope atomic load: bypasses any stale clean cache lines
      const float L = __hip_atomic_load(&lg[i], __ATOMIC_RELAXED, __HIP_MEMORY_SCOPE_AGENT);
      out[i] = L;
      out[B + i] = 1.0f / (1.0f + expf(-L));
    }
  }
}

// ------------------------- launcher ----------------------------------------

extern "C" void kernel_launch(void* const* d_in, const int* in_sizes, int n_in,
                              void* d_out, int out_size, void* d_ws, size_t ws_size,
                              hipStream_t stream) {
  const float* X   = (const float*)d_in[0];
  const float* D   = (const float*)d_in[1];
  const float* r   = (const float*)d_in[2];
  const float* g_w = (const float*)d_in[3];
  const float* g_b = (const float*)d_in[4];
  const float* h_w = (const float*)d_in[5];
  const float* h_b = (const float*)d_in[6];
  float* out = (float*)d_out;

  // ws layout (bytes), 256-aligned, total ~25.1 MB
  char* ws = (char*)d_ws;
  __bf16* Eb     = (__bf16*)(ws + 0);          // 24096*512*2 = 24,674,304
  float*  norm2p = (float*) (ws + 24674304);   // 4*24576*4  =    393,216
  float*  lg     = (float*) (ws + 25067520);   // 4096*4     =     16,384

  // 1. embedding GEMM straight from fp32 inputs (+ lg zeroing by block 0)
  k_embed<<<4 * 192, 256, 0, stream>>>(X, D, g_w, g_b, Eb, norm2p, lg);

  // 2. cosine^3-weighted retrieval + last-block finalize
  k_minerva<<<MINERVA_BLOCKS, 256, 0, stream>>>(Eb, norm2p, r, h_w, h_b, lg, out);
}

// Round 6
// 286.580 us; speedup vs baseline: 1.2683x; 1.2683x over previous
//
#include <hip/hip_runtime.h>
#include <cstdint>

// ---------------------------------------------------------------------------
// minerva_transform: logits = (l2(Xe) @ l2(De)^T)^3 @ rh ; preds = sigmoid
// R6: 4 dispatches, dispatch-boundary ordering only (R4/R5 cross-block sync
// experiments both lost).  New: launch_bounds(256,4) -> 4 blocks/CU (R3 was
// self-capped at 3), zero global atomics (lgp partial slabs + norm2p slots),
// rh inline, finalize sums 157 partials.  GEMM cores = R3's proven 112us
// structure (BK=64, XOR-swizzled conflict-free LDS, global_load_lds w=16).
// ---------------------------------------------------------------------------

typedef __attribute__((ext_vector_type(4))) float  f32x4;
typedef __attribute__((ext_vector_type(8))) __bf16 bf16x8;
typedef __attribute__((ext_vector_type(4))) __bf16 bf16x4;

constexpr int B = 4096, N = 20000, F = 768, E = 512;
constexpr int NROWS = 24576;   // padded g-rows (192 row-tiles)
constexpr int NT = 157, MT = 32, W = 20;

#define AS1CAST(p) ((__attribute__((address_space(1))) unsigned int*)(uintptr_t)(p))
#define AS3CAST(p) ((__attribute__((address_space(3))) unsigned int*)(uintptr_t)(p))

__device__ __forceinline__ void gload_lds16(const void* g, void* l) {
  __builtin_amdgcn_global_load_lds(AS1CAST(g), AS3CAST(l), 16, 0, 0);
}

// ------------------------- prep: fp32 -> bf16 ------------------------------

__global__ void k_prep(const float* __restrict__ X, const float* __restrict__ D,
                       const float* __restrict__ G,
                       __bf16* __restrict__ Xb, __bf16* __restrict__ Db,
                       __bf16* __restrict__ Gb) {
  const int t = blockIdx.x * blockDim.x + threadIdx.x;
  const int stride = gridDim.x * blockDim.x;
  constexpr int nX = B * F / 4, nD = N * F / 4, nG = E * F / 4;
  constexpr int tot = nX + nD + nG;
  for (int i = t; i < tot; i += stride) {
    const float4* src; bf16x4* dst; int off;
    if (i < nX)           { src = (const float4*)X; dst = (bf16x4*)Xb; off = i; }
    else if (i < nX + nD) { src = (const float4*)D; dst = (bf16x4*)Db; off = i - nX; }
    else                  { src = (const float4*)G; dst = (bf16x4*)Gb; off = i - nX - nD; }
    float4 v = src[off];
    bf16x4 o;
    o[0] = (__bf16)v.x; o[1] = (__bf16)v.y; o[2] = (__bf16)v.z; o[3] = (__bf16)v.w;
    dst[off] = o;
  }
}

// ------------------------- embedding GEMM ----------------------------------
// blockIdx.y = row-tile (0..31 X, 32..188 D), blockIdx.x = e-tile (0..3).
// Eb[g,e] = bf16(sum_k A[m,k]G[e,k] + b[e]);  norm2p[bx*NROWS+g] = partial
// sumsq (race-free slot per (bx,row), no atomics, no zero-init needed).

__global__ __launch_bounds__(256, 4)
void k_embed(const __bf16* __restrict__ Xb, const __bf16* __restrict__ Db,
             const __bf16* __restrict__ Gb, const float* __restrict__ bias,
             __bf16* __restrict__ Eb, float* __restrict__ norm2p) {
  __shared__ __bf16 As[128 * 64];
  __shared__ __bf16 Bs[128 * 64];
  __shared__ float lsum[128];
  const int tid  = threadIdx.x;
  const int wave = tid >> 6;
  const int lane = tid & 63;
  const int by = blockIdx.y;
  const int bx = blockIdx.x;
  const bool isX = (by < 32);
  const __bf16* A = isX ? Xb : Db;
  const int m0 = isX ? by * 128 : (by - 32) * 128;
  const int Mr = isX ? B : N;
  const int g0 = by * 128;
  const int n0 = bx * 128;
  if (tid < 128) lsum[tid] = 0.0f;

  const int srow = tid >> 3;
  const int scg  = (tid & 7) ^ (srow & 7);
  const __bf16* ga[4]; const __bf16* gb[4]; int li[4];
#pragma unroll
  for (int q = 0; q < 4; ++q) {
    const int row = srow + 32 * q;
    int arow = m0 + row; if (arow >= Mr) arow = Mr - 1;
    ga[q] = A  + (size_t)arow * F + scg * 8;
    gb[q] = Gb + (size_t)(n0 + row) * F + scg * 8;
    li[q] = q * 2048 + tid * 8;
  }

  const int mw = (wave & 1) * 64;
  const int nw = (wave >> 1) * 64;
  const int quad = lane >> 4;
  const int l15  = lane & 15;
  f32x4 acc[4][4] = {};

  for (int kb = 0; kb < F; kb += 64) {
#pragma unroll
    for (int q = 0; q < 4; ++q) gload_lds16(ga[q] + kb, &As[li[q]]);
#pragma unroll
    for (int q = 0; q < 4; ++q) gload_lds16(gb[q] + kb, &Bs[li[q]]);
    __syncthreads();
#pragma unroll
    for (int h = 0; h < 2; ++h) {
      bf16x8 af[4], bfr[4];
#pragma unroll
      for (int i = 0; i < 4; ++i) {
        const int rr = mw + i * 16 + l15;
        af[i] = *(const bf16x8*)&As[rr * 64 + ((quad + h * 4) ^ (rr & 7)) * 8];
      }
#pragma unroll
      for (int j = 0; j < 4; ++j) {
        const int rr = nw + j * 16 + l15;
        bfr[j] = *(const bf16x8*)&Bs[rr * 64 + ((quad + h * 4) ^ (rr & 7)) * 8];
      }
#pragma unroll
      for (int i = 0; i < 4; ++i)
#pragma unroll
        for (int j = 0; j < 4; ++j)
          acc[i][j] = __builtin_amdgcn_mfma_f32_16x16x32_bf16(af[i], bfr[j], acc[i][j], 0, 0, 0);
    }
    __syncthreads();
  }

  // epilogue: bf16 store + row sum-of-squares (C/D: col=l15, row=quad*4+rr)
#pragma unroll
  for (int i = 0; i < 4; ++i) {
    float part[4] = {0.0f, 0.0f, 0.0f, 0.0f};
#pragma unroll
    for (int j = 0; j < 4; ++j) {
      const int col = n0 + nw + j * 16 + l15;
      const float bv = bias[col];
#pragma unroll
      for (int rr = 0; rr < 4; ++rr) {
        const int row = mw + i * 16 + quad * 4 + rr;
        if (m0 + row < Mr) {
          const __bf16 hv = (__bf16)(acc[i][j][rr] + bv);
          Eb[(size_t)(g0 + row) * E + col] = hv;
          const float vb = (float)hv;
          part[rr] += vb * vb;
        }
      }
    }
#pragma unroll
    for (int rr = 0; rr < 4; ++rr) {
      float v = part[rr];
      v += __shfl_xor(v, 1);
      v += __shfl_xor(v, 2);
      v += __shfl_xor(v, 4);
      v += __shfl_xor(v, 8);
      if (l15 == 0) atomicAdd(&lsum[mw + i * 16 + quad * 4 + rr], v);  // LDS only
    }
  }
  __syncthreads();
  if (tid < 128) norm2p[(size_t)bx * NROWS + g0 + tid] = lsum[tid];
}

// ------------------------- fused Minerva GEMM ------------------------------
// R3 panel ordering (m-fast within W=20 n-tile panels).  Zero global atomics:
// block (mt,nt) writes its own lgp[nt*B + m0..m0+127] partial slab.

__global__ __launch_bounds__(256, 4)
void k_minerva(const __bf16* __restrict__ Eb, const float* __restrict__ norm2p,
               const float* __restrict__ r, const float* __restrict__ hw,
               const float* __restrict__ hb, float* __restrict__ lgp) {
  __shared__ __bf16 As[128 * 64];
  __shared__ __bf16 Bs[128 * 64];
  __shared__ float lsum[128];
  const int tid  = threadIdx.x;
  const int lane = tid & 63;
  const int wave = tid >> 6;

  // panel decomposition, m-fast within panel
  const int bid   = blockIdx.x;
  const int panel = bid / (W * MT);
  const int bn    = panel * W;
  const int rem   = bid - panel * (W * MT);
  const int mt    = rem % MT;
  const int nt    = bn + rem / MT;
  const int m0 = mt * 128, n0 = nt * 128;
  if (tid < 128) lsum[tid] = 0.0f;

  const __bf16* Xe = Eb;
  const __bf16* De = Eb + (size_t)B * E;
  const int srow = tid >> 3;
  const int scg  = (tid & 7) ^ (srow & 7);
  const __bf16* ga[4]; const __bf16* gb[4]; int li[4];
#pragma unroll
  for (int q = 0; q < 4; ++q) {
    const int row = srow + 32 * q;
    const int arow = m0 + row;                     // < 4096 always
    int brow = n0 + row; if (brow >= N) brow = N - 1;
    ga[q] = Xe + (size_t)arow * E + scg * 8;
    gb[q] = De + (size_t)brow * E + scg * 8;
    li[q] = q * 2048 + tid * 8;
  }

  const int mw = (wave & 1) * 64;
  const int nw = (wave >> 1) * 64;
  const int quad = lane >> 4;
  const int l15  = lane & 15;
  f32x4 acc[4][4] = {};

  for (int kb = 0; kb < E; kb += 64) {
#pragma unroll
    for (int q = 0; q < 4; ++q) gload_lds16(ga[q] + kb, &As[li[q]]);
#pragma unroll
    for (int q = 0; q < 4; ++q) gload_lds16(gb[q] + kb, &Bs[li[q]]);
    __syncthreads();
#pragma unroll
    for (int h = 0; h < 2; ++h) {
      bf16x8 af[4], bfr[4];
#pragma unroll
      for (int i = 0; i < 4; ++i) {
        const int rr = mw + i * 16 + l15;
        af[i] = *(const bf16x8*)&As[rr * 64 + ((quad + h * 4) ^ (rr & 7)) * 8];
      }
#pragma unroll
      for (int j = 0; j < 4; ++j) {
        const int rr = nw + j * 16 + l15;
        bfr[j] = *(const bf16x8*)&Bs[rr * 64 + ((quad + h * 4) ^ (rr & 7)) * 8];
      }
#pragma unroll
      for (int i = 0; i < 4; ++i)
#pragma unroll
        for (int j = 0; j < 4; ++j)
          acc[i][j] = __builtin_amdgcn_mfma_f32_16x16x32_bf16(af[i], bfr[j], acc[i][j], 0, 0, 0);
    }
    __syncthreads();
  }

  // epilogue: s^3*rh = acc^3 * ix^3 * (id^3*rh);  rh inline from r
  const float hwv = hw[0], hbv = hb[0];
  float id3rh[4];
#pragma unroll
  for (int j = 0; j < 4; ++j) {
    const int col = n0 + nw + j * 16 + l15;
    if (col < N) {
      const int gr = B + col;
      const float nd2 = norm2p[gr] + norm2p[NROWS + gr]
                      + norm2p[2 * NROWS + gr] + norm2p[3 * NROWS + gr];
      const float id = 1.0f / fmaxf(sqrtf(nd2), 1e-12f);
      const float rhv = (2.0f * r[col] - 1.0f) * hwv + hbv;
      id3rh[j] = id * id * id * rhv;
    } else id3rh[j] = 0.0f;   // kills padded/clamped cols
  }
#pragma unroll
  for (int i = 0; i < 4; ++i) {
    float ix3[4];
#pragma unroll
    for (int rr = 0; rr < 4; ++rr) {
      const int row = m0 + mw + i * 16 + quad * 4 + rr;   // < 4096
      const float nx2 = norm2p[row] + norm2p[NROWS + row]
                      + norm2p[2 * NROWS + row] + norm2p[3 * NROWS + row];
      const float ix = 1.0f / fmaxf(sqrtf(nx2), 1e-12f);
      ix3[rr] = ix * ix * ix;
    }
    float part[4] = {0.0f, 0.0f, 0.0f, 0.0f};
#pragma unroll
    for (int j = 0; j < 4; ++j)
#pragma unroll
      for (int rr = 0; rr < 4; ++rr) {
        const float a = acc[i][j][rr];
        part[rr] = fmaf(a * a * a, id3rh[j], part[rr]);
      }
#pragma unroll
    for (int rr = 0; rr < 4; ++rr) {
      float v = part[rr] * ix3[rr];
      v += __shfl_xor(v, 1);
      v += __shfl_xor(v, 2);
      v += __shfl_xor(v, 4);
      v += __shfl_xor(v, 8);
      if (l15 == 0) atomicAdd(&lsum[mw + i * 16 + quad * 4 + rr], v);  // LDS only
    }
  }
  __syncthreads();
  if (tid < 128) lgp[(size_t)nt * B + m0 + tid] = lsum[tid];   // own slab, no atomics
}

// ------------------------- finalize ----------------------------------------

__global__ void k_finalize(const float* __restrict__ lgp, float* __restrict__ out) {
  const int m = blockIdx.x * 256 + threadIdx.x;   // grid 16 -> 4096 threads
  float L = 0.0f;
  for (int nt = 0; nt < NT; ++nt) L += lgp[(size_t)nt * B + m];
  out[m] = L;
  out[B + m] = 1.0f / (1.0f + expf(-L));
}

// ------------------------- launcher ----------------------------------------

extern "C" void kernel_launch(void* const* d_in, const int* in_sizes, int n_in,
                              void* d_out, int out_size, void* d_ws, size_t ws_size,
                              hipStream_t stream) {
  const float* X   = (const float*)d_in[0];
  const float* D   = (const float*)d_in[1];
  const float* r   = (const float*)d_in[2];
  const float* g_w = (const float*)d_in[3];
  const float* g_b = (const float*)d_in[4];
  const float* h_w = (const float*)d_in[5];
  const float* h_b = (const float*)d_in[6];
  float* out = (float*)d_out;

  // ws layout (bytes), 256-aligned, total ~65.4 MB
  char* ws = (char*)d_ws;
  __bf16* Xb     = (__bf16*)(ws + 0);            // 4096*768*2   = 6,291,456
  __bf16* Db     = (__bf16*)(ws + 6291456);      // 20000*768*2  = 30,720,000
  __bf16* Gb     = (__bf16*)(ws + 37011456);     // 512*768*2    = 786,432
  __bf16* Eb     = (__bf16*)(ws + 37797888);     // 24096*512*2  = 24,674,304
  float*  norm2p = (float*) (ws + 62472192);     // 4*24576*4    = 393,216
  float*  lgp    = (float*) (ws + 62865408);     // 157*4096*4   = 2,571,264

  // 1. fp32 -> bf16 converts
  k_prep<<<2048, 256, 0, stream>>>(X, D, g_w, Xb, Db, Gb);

  // 2. embedding GEMM, bf16 out + race-free norm2 partial slots
  k_embed<<<dim3(4, 192), 256, 0, stream>>>(Xb, Db, Gb, g_b, Eb, norm2p);

  // 3. cosine^3-weighted retrieval -> per-(nt) partial logit slabs
  k_minerva<<<NT * MT, 256, 0, stream>>>(Eb, norm2p, r, h_w, h_b, lgp);

  // 4. reduce partials + sigmoid
  k_finalize<<<B / 256, 256, 0, stream>>>(lgp, out);
}

// Round 7
// 279.044 us; speedup vs baseline: 1.3025x; 1.0270x over previous
//
#include <hip/hip_runtime.h>
#include <cstdint>

// ---------------------------------------------------------------------------
// minerva_transform: logits = (l2(Xe) @ l2(De)^T)^3 @ rh ; preds = sigmoid
// R7: 3 dispatches.
//   1) k_embed: fp32 X/D/g_w read directly, fp32->bf16 cvt in LDS staging
//      (R5-verified), XCD-co-located grid (4 e-tiles of a row-tile share an
//      XCD: bids stride 192 = 0 mod 8), writes Eb bf16 + norm2p slots.
//   2) k_minerva: R3's 112us structure (BK=64, XOR-swizzled LDS, panel W=20
//      m-fast, launch_bounds(256,3)), float4 norm2p loads, lgp slab out.
//   3) k_finalize: 157-partial sum + sigmoid.
// No global atomics anywhere; no zero-init dependencies; replay-safe.
// ---------------------------------------------------------------------------

typedef __attribute__((ext_vector_type(4))) float  f32x4;
typedef __attribute__((ext_vector_type(8))) __bf16 bf16x8;

constexpr int B = 4096, N = 20000, F = 768, E = 512;
constexpr int NROWS = 24576;   // padded g-rows (192 row-tiles)
constexpr int NT = 157, MT = 32, W = 20;

#define AS1CAST(p) ((__attribute__((address_space(1))) unsigned int*)(uintptr_t)(p))
#define AS3CAST(p) ((__attribute__((address_space(3))) unsigned int*)(uintptr_t)(p))

__device__ __forceinline__ void gload_lds16(const void* g, void* l) {
  __builtin_amdgcn_global_load_lds(AS1CAST(g), AS3CAST(l), 16, 0, 0);
}

// ------------------------- embedding GEMM (fp32 in) ------------------------
// bid = bx*192 + by : by = row-tile (0..31 X, 32..188 D, 189..191 pad),
// bx = e-tile.  The 4 bx-blocks of one by differ by 192 = 0 mod 8 -> same XCD.
// Stages fp32 -> bf16 into XOR-swizzled LDS (VALU cvt; no prep pass).

__global__ __launch_bounds__(256, 3)
void k_embed(const float* __restrict__ X, const float* __restrict__ D,
             const float* __restrict__ G, const float* __restrict__ bias,
             __bf16* __restrict__ Eb, float* __restrict__ norm2p) {
  __shared__ __bf16 As[128 * 64];
  __shared__ __bf16 Bs[128 * 64];
  __shared__ float lsum[128];
  const int tid  = threadIdx.x;
  const int bid  = blockIdx.x;
  const int wave = tid >> 6;
  const int lane = tid & 63;
  const int bx = bid / 192;     // e-tile 0..3
  const int by = bid % 192;     // row-tile (XCD-pinned: by&7)
  const bool isX = (by < 32);
  const float* A = isX ? X : D;
  const int m0 = isX ? by * 128 : (by - 32) * 128;
  const int Mr = isX ? B : N;
  const int g0 = by * 128;
  const int n0 = bx * 128;
  if (tid < 128) lsum[tid] = 0.0f;

  // staging: thread t -> rows rbase+32q, colgrp cg (8 elems = 16B),
  // stored at swizzled slot cg^(row&7)  (row&7 == rbase&7)
  const int cg    = tid & 7;
  const int rbase = tid >> 3;
  const int sw    = (cg ^ (rbase & 7)) * 8;
  size_t aoff[4], boff[4];
  int    lidx[4];
#pragma unroll
  for (int q = 0; q < 4; ++q) {
    const int rt = rbase + 32 * q;
    int arow = m0 + rt; if (arow >= Mr) arow = Mr - 1;
    aoff[q] = (size_t)arow * F + cg * 8;
    boff[q] = (size_t)(n0 + rt) * F + cg * 8;
    lidx[q] = rt * 64 + sw;
  }

  const int mw = (wave & 1) * 64;
  const int nw = (wave >> 1) * 64;
  const int quad = lane >> 4;
  const int l15  = lane & 15;
  f32x4 acc[4][4] = {};

  for (int kb = 0; kb < F; kb += 64) {
#pragma unroll
    for (int q = 0; q < 4; ++q) {
      const float4 v0 = *(const float4*)(A + aoff[q] + kb);
      const float4 v1 = *(const float4*)(A + aoff[q] + kb + 4);
      bf16x8 t;
      t[0] = (__bf16)v0.x; t[1] = (__bf16)v0.y; t[2] = (__bf16)v0.z; t[3] = (__bf16)v0.w;
      t[4] = (__bf16)v1.x; t[5] = (__bf16)v1.y; t[6] = (__bf16)v1.z; t[7] = (__bf16)v1.w;
      *(bf16x8*)&As[lidx[q]] = t;
    }
#pragma unroll
    for (int q = 0; q < 4; ++q) {
      const float4 v0 = *(const float4*)(G + boff[q] + kb);
      const float4 v1 = *(const float4*)(G + boff[q] + kb + 4);
      bf16x8 t;
      t[0] = (__bf16)v0.x; t[1] = (__bf16)v0.y; t[2] = (__bf16)v0.z; t[3] = (__bf16)v0.w;
      t[4] = (__bf16)v1.x; t[5] = (__bf16)v1.y; t[6] = (__bf16)v1.z; t[7] = (__bf16)v1.w;
      *(bf16x8*)&Bs[lidx[q]] = t;
    }
    __syncthreads();
#pragma unroll
    for (int h = 0; h < 2; ++h) {
      bf16x8 af[4], bfr[4];
#pragma unroll
      for (int i = 0; i < 4; ++i) {
        const int rr = mw + i * 16 + l15;
        af[i] = *(const bf16x8*)&As[rr * 64 + ((quad + h * 4) ^ (rr & 7)) * 8];
      }
#pragma unroll
      for (int j = 0; j < 4; ++j) {
        const int rr = nw + j * 16 + l15;
        bfr[j] = *(const bf16x8*)&Bs[rr * 64 + ((quad + h * 4) ^ (rr & 7)) * 8];
      }
#pragma unroll
      for (int i = 0; i < 4; ++i)
#pragma unroll
        for (int j = 0; j < 4; ++j)
          acc[i][j] = __builtin_amdgcn_mfma_f32_16x16x32_bf16(af[i], bfr[j], acc[i][j], 0, 0, 0);
    }
    __syncthreads();
  }

  // epilogue: bf16 store + row sum-of-squares (C/D: col=l15, row=quad*4+rr)
#pragma unroll
  for (int i = 0; i < 4; ++i) {
    float part[4] = {0.0f, 0.0f, 0.0f, 0.0f};
#pragma unroll
    for (int j = 0; j < 4; ++j) {
      const int col = n0 + nw + j * 16 + l15;
      const float bv = bias[col];
#pragma unroll
      for (int rr = 0; rr < 4; ++rr) {
        const int row = mw + i * 16 + quad * 4 + rr;
        if (m0 + row < Mr) {
          const __bf16 hv = (__bf16)(acc[i][j][rr] + bv);
          Eb[(size_t)(g0 + row) * E + col] = hv;
          const float vb = (float)hv;
          part[rr] += vb * vb;
        }
      }
    }
#pragma unroll
    for (int rr = 0; rr < 4; ++rr) {
      float v = part[rr];
      v += __shfl_xor(v, 1);
      v += __shfl_xor(v, 2);
      v += __shfl_xor(v, 4);
      v += __shfl_xor(v, 8);
      if (l15 == 0) atomicAdd(&lsum[mw + i * 16 + quad * 4 + rr], v);  // LDS only
    }
  }
  __syncthreads();
  if (tid < 128) norm2p[(size_t)bx * NROWS + g0 + tid] = lsum[tid];  // race-free slot
}

// ------------------------- fused Minerva GEMM ------------------------------
// R3 panel ordering (m-fast within W=20 n-tile panels), launch_bounds(256,3).
// Block (mt,nt) writes its own lgp[nt*B + m0..m0+127] slab (no atomics).

__global__ __launch_bounds__(256, 3)
void k_minerva(const __bf16* __restrict__ Eb, const float* __restrict__ norm2p,
               const float* __restrict__ r, const float* __restrict__ hw,
               const float* __restrict__ hb, float* __restrict__ lgp) {
  __shared__ __bf16 As[128 * 64];
  __shared__ __bf16 Bs[128 * 64];
  __shared__ float lsum[128];
  const int tid  = threadIdx.x;
  const int lane = tid & 63;
  const int wave = tid >> 6;

  // panel decomposition, m-fast within panel
  const int bid   = blockIdx.x;
  const int panel = bid / (W * MT);
  const int bn    = panel * W;
  const int rem   = bid - panel * (W * MT);
  const int mt    = rem % MT;
  const int nt    = bn + rem / MT;
  const int m0 = mt * 128, n0 = nt * 128;
  if (tid < 128) lsum[tid] = 0.0f;

  const __bf16* Xe = Eb;
  const __bf16* De = Eb + (size_t)B * E;
  const int srow = tid >> 3;
  const int scg  = (tid & 7) ^ (srow & 7);
  const __bf16* ga[4]; const __bf16* gb[4]; int li[4];
#pragma unroll
  for (int q = 0; q < 4; ++q) {
    const int row = srow + 32 * q;
    const int arow = m0 + row;                     // < 4096 always
    int brow = n0 + row; if (brow >= N) brow = N - 1;
    ga[q] = Xe + (size_t)arow * E + scg * 8;
    gb[q] = De + (size_t)brow * E + scg * 8;
    li[q] = q * 2048 + tid * 8;
  }

  const int mw = (wave & 1) * 64;
  const int nw = (wave >> 1) * 64;
  const int quad = lane >> 4;
  const int l15  = lane & 15;
  f32x4 acc[4][4] = {};

  for (int kb = 0; kb < E; kb += 64) {
#pragma unroll
    for (int q = 0; q < 4; ++q) gload_lds16(ga[q] + kb, &As[li[q]]);
#pragma unroll
    for (int q = 0; q < 4; ++q) gload_lds16(gb[q] + kb, &Bs[li[q]]);
    __syncthreads();
#pragma unroll
    for (int h = 0; h < 2; ++h) {
      bf16x8 af[4], bfr[4];
#pragma unroll
      for (int i = 0; i < 4; ++i) {
        const int rr = mw + i * 16 + l15;
        af[i] = *(const bf16x8*)&As[rr * 64 + ((quad + h * 4) ^ (rr & 7)) * 8];
      }
#pragma unroll
      for (int j = 0; j < 4; ++j) {
        const int rr = nw + j * 16 + l15;
        bfr[j] = *(const bf16x8*)&Bs[rr * 64 + ((quad + h * 4) ^ (rr & 7)) * 8];
      }
#pragma unroll
      for (int i = 0; i < 4; ++i)
#pragma unroll
        for (int j = 0; j < 4; ++j)
          acc[i][j] = __builtin_amdgcn_mfma_f32_16x16x32_bf16(af[i], bfr[j], acc[i][j], 0, 0, 0);
    }
    __syncthreads();
  }

  // epilogue: s^3*rh = acc^3 * ix^3 * (id^3*rh);  rh inline from r
  const float hwv = hw[0], hbv = hb[0];
  float id3rh[4];
#pragma unroll
  for (int j = 0; j < 4; ++j) {
    const int col = n0 + nw + j * 16 + l15;
    if (col < N) {
      const int gr = B + col;
      const float nd2 = norm2p[gr] + norm2p[NROWS + gr]
                      + norm2p[2 * NROWS + gr] + norm2p[3 * NROWS + gr];
      const float id = 1.0f / fmaxf(sqrtf(nd2), 1e-12f);
      const float rhv = (2.0f * r[col] - 1.0f) * hwv + hbv;
      id3rh[j] = id * id * id * rhv;
    } else id3rh[j] = 0.0f;   // kills padded/clamped cols
  }
#pragma unroll
  for (int i = 0; i < 4; ++i) {
    // 4-slot norm sum as float4 loads (rows quad*4..quad*4+3 are contiguous)
    const int rowb = m0 + mw + i * 16 + quad * 4;
    const float4 s0 = *(const float4*)(norm2p + rowb);
    const float4 s1 = *(const float4*)(norm2p + NROWS + rowb);
    const float4 s2 = *(const float4*)(norm2p + 2 * NROWS + rowb);
    const float4 s3 = *(const float4*)(norm2p + 3 * NROWS + rowb);
    const float nx2[4] = { s0.x + s1.x + s2.x + s3.x, s0.y + s1.y + s2.y + s3.y,
                           s0.z + s1.z + s2.z + s3.z, s0.w + s1.w + s2.w + s3.w };
    float part[4] = {0.0f, 0.0f, 0.0f, 0.0f};
#pragma unroll
    for (int j = 0; j < 4; ++j)
#pragma unroll
      for (int rr = 0; rr < 4; ++rr) {
        const float a = acc[i][j][rr];
        part[rr] = fmaf(a * a * a, id3rh[j], part[rr]);
      }
#pragma unroll
    for (int rr = 0; rr < 4; ++rr) {
      const float ix = 1.0f / fmaxf(sqrtf(nx2[rr]), 1e-12f);
      float v = part[rr] * (ix * ix * ix);
      v += __shfl_xor(v, 1);
      v += __shfl_xor(v, 2);
      v += __shfl_xor(v, 4);
      v += __shfl_xor(v, 8);
      if (l15 == 0) atomicAdd(&lsum[mw + i * 16 + quad * 4 + rr], v);  // LDS only
    }
  }
  __syncthreads();
  if (tid < 128) lgp[(size_t)nt * B + m0 + tid] = lsum[tid];   // own slab
}

// ------------------------- finalize ----------------------------------------

__global__ void k_finalize(const float* __restrict__ lgp, float* __restrict__ out) {
  const int m = blockIdx.x * 256 + threadIdx.x;   // grid 16 -> 4096 threads
  float L = 0.0f;
  for (int nt = 0; nt < NT; ++nt) L += lgp[(size_t)nt * B + m];
  out[m] = L;
  out[B + m] = 1.0f / (1.0f + expf(-L));
}

// ------------------------- launcher ----------------------------------------

extern "C" void kernel_launch(void* const* d_in, const int* in_sizes, int n_in,
                              void* d_out, int out_size, void* d_ws, size_t ws_size,
                              hipStream_t stream) {
  const float* X   = (const float*)d_in[0];
  const float* D   = (const float*)d_in[1];
  const float* r   = (const float*)d_in[2];
  const float* g_w = (const float*)d_in[3];
  const float* g_b = (const float*)d_in[4];
  const float* h_w = (const float*)d_in[5];
  const float* h_b = (const float*)d_in[6];
  float* out = (float*)d_out;

  // ws layout (bytes), 256-aligned, total ~27.6 MB
  char* ws = (char*)d_ws;
  __bf16* Eb     = (__bf16*)(ws + 0);          // 24096*512*2 = 24,674,304
  float*  norm2p = (float*) (ws + 24674304);   // 4*24576*4  =    393,216
  float*  lgp    = (float*) (ws + 25067520);   // 157*4096*4 =  2,571,264

  // 1. embedding GEMM straight from fp32 inputs
  k_embed<<<4 * 192, 256, 0, stream>>>(X, D, g_w, g_b, Eb, norm2p);

  // 2. cosine^3-weighted retrieval -> per-nt partial logit slabs
  k_minerva<<<NT * MT, 256, 0, stream>>>(Eb, norm2p, r, h_w, h_b, lgp);

  // 3. reduce partials + sigmoid
  k_finalize<<<B / 256, 256, 0, stream>>>(lgp, out);
}